// Round 10
// baseline (1271.089 us; speedup 1.0000x reference)
//
#include <hip/hip_runtime.h>

#define NN   30000
#define NE   480000
#define NR   7
#define NSEG (NN*NR)
#define DH   512
#define DIN  21
#define EPSB 1e-5f
#define BK   32
#define KSEG 3584          // 7*512 gathered columns (self handled from hbf)

typedef __attribute__((ext_vector_type(8))) short bf16x8;
typedef __attribute__((ext_vector_type(8))) unsigned short u16x8;
typedef __attribute__((ext_vector_type(4))) float f32x4;
typedef unsigned short ushortT;

static inline size_t align256(size_t x){ return (x + 255) & ~(size_t)255; }

__device__ inline float bf2f(ushortT u){
    unsigned int i = ((unsigned int)u) << 16; float f; __builtin_memcpy(&f, &i, 4); return f;
}
__device__ inline ushortT f2bf(float f){
    unsigned int i; __builtin_memcpy(&i, &f, 4);
    unsigned int r = i + 0x7FFFu + ((i >> 16) & 1u);
    return (ushortT)(r >> 16);
}

__device__ inline void load_lds16(const ushortT* g, ushortT* l){
    __builtin_amdgcn_global_load_lds((const __attribute__((address_space(1))) unsigned int*)g,
                                     (__attribute__((address_space(3))) unsigned int*)l,
                                     16, 0, 0);
}

// ---------------- CSR build (counting sort by seg = dst*7+rel) ----------------

__global__ void hist_k(const int* __restrict__ dst, const int* __restrict__ rel,
                       int* __restrict__ counts){
    int e = blockIdx.x*256 + threadIdx.x;
    if (e < NE) atomicAdd(&counts[dst[e]*NR + rel[e]], 1);
}

__global__ void scan1_k(const int* __restrict__ counts, int* __restrict__ bsum){
    __shared__ int sd[256];
    int t = threadIdx.x;
    int base = blockIdx.x*1024 + t*4;
    int s = 0;
#pragma unroll
    for (int i = 0; i < 4; i++){ int idx = base + i; if (idx < NSEG) s += counts[idx]; }
    sd[t] = s; __syncthreads();
    for (int off = 128; off > 0; off >>= 1){
        if (t < off) sd[t] += sd[t+off];
        __syncthreads();
    }
    if (t == 0) bsum[blockIdx.x] = sd[0];
}

__global__ void scan2_k(int* __restrict__ bsum, int nb, int* __restrict__ seg_start){
    __shared__ int sd[256];
    int t = threadIdx.x;
    int v = (t < nb) ? bsum[t] : 0;
    sd[t] = v; __syncthreads();
    for (int off = 1; off < 256; off <<= 1){
        int x = sd[t];
        if (t >= off) x += sd[t-off];
        __syncthreads();
        sd[t] = x; __syncthreads();
    }
    if (t < nb) bsum[t] = (t == 0) ? 0 : sd[t-1];
    if (t == 0) seg_start[NSEG] = NE;
}

__global__ void scan3_k(const int* __restrict__ counts, const int* __restrict__ bsum,
                        int* __restrict__ seg_start){
    __shared__ int sd[256];
    int t = threadIdx.x;
    int base = blockIdx.x*1024 + t*4;
    int v[4]; int s = 0;
#pragma unroll
    for (int i = 0; i < 4; i++){ int idx = base + i; v[i] = (idx < NSEG) ? counts[idx] : 0; s += v[i]; }
    sd[t] = s; __syncthreads();
    for (int off = 1; off < 256; off <<= 1){
        int x = sd[t];
        if (t >= off) x += sd[t-off];
        __syncthreads();
        sd[t] = x; __syncthreads();
    }
    int excl = sd[t] - s + bsum[blockIdx.x];
#pragma unroll
    for (int i = 0; i < 4; i++){
        int idx = base + i;
        if (idx < NSEG){ seg_start[idx] = excl; excl += v[i]; }
    }
}

__global__ void scatter_k(const int* __restrict__ src, const int* __restrict__ dst,
                          const int* __restrict__ rel, const int* __restrict__ seg_start,
                          int* __restrict__ cursor, int* __restrict__ src_sorted){
    int e = blockIdx.x*256 + threadIdx.x;
    if (e < NE){
        int s = dst[e]*NR + rel[e];
        int pos = seg_start[s] + atomicAdd(&cursor[s], 1);
        src_sorted[pos] = src[e];
    }
}

// ---------------- layer 0: segment sum d=21, Kp=192 (147 upd | 21 self | 24 pad) ----------------

__global__ void segsum21b_k(const float* __restrict__ x0,
                            const int* __restrict__ seg_start, const int* __restrict__ src_sorted,
                            ushortT* __restrict__ Acat){
    int n = blockIdx.x;
    int t = threadIdx.x;   // 64
    ushortT* arow = Acat + (long)n*192;
    if (t < DIN){
        int sb = n*NR;
        int e0 = seg_start[sb];
#pragma unroll
        for (int r = 0; r < NR; r++){
            int e1 = seg_start[sb + r + 1];
            float a = 0.f;
            for (int e = e0; e < e1; e++) a += x0[(long)src_sorted[e]*DIN + t];
            e0 = e1;
            arow[r*DIN + t] = f2bf(a);
        }
        arow[7*DIN + t] = f2bf(x0[(long)n*DIN + t]);
    }
    if (t >= 40) arow[168 + (t - 40)] = 0;   // zero pad cols 168..191
}

// ---------------- layers 1,2: one WAVE per node, 7-rel segment sum → Acat[*,3584] ----------------

__global__ __launch_bounds__(256)
void segsum_wave_k(const ushortT* __restrict__ hbf,
                   const int* __restrict__ seg_start, const int* __restrict__ src_sorted,
                   ushortT* __restrict__ Acat, int c0, int cn){
    int wid = (blockIdx.x*256 + threadIdx.x) >> 6;
    if (wid >= cn) return;
    const int n = c0 + wid;
    const int lane = (threadIdx.x & 63);
    const int co = lane*8;

    int sb[8];
#pragma unroll
    for (int i = 0; i < 8; i++) sb[i] = seg_start[n*NR + i];

    ushortT* arow = Acat + (long)wid*KSEG + co;
#pragma unroll
    for (int r = 0; r < NR; r++){
        float a[8];
#pragma unroll
        for (int j = 0; j < 8; j++) a[j] = 0.f;
        int e = sb[r], e1 = sb[r+1];
        for (; e + 3 < e1; e += 4){
            u16x8 v0 = *reinterpret_cast<const u16x8*>(hbf + (long)src_sorted[e  ]*DH + co);
            u16x8 v1 = *reinterpret_cast<const u16x8*>(hbf + (long)src_sorted[e+1]*DH + co);
            u16x8 v2 = *reinterpret_cast<const u16x8*>(hbf + (long)src_sorted[e+2]*DH + co);
            u16x8 v3 = *reinterpret_cast<const u16x8*>(hbf + (long)src_sorted[e+3]*DH + co);
#pragma unroll
            for (int j = 0; j < 8; j++)
                a[j] += (bf2f((ushortT)v0[j]) + bf2f((ushortT)v1[j]))
                      + (bf2f((ushortT)v2[j]) + bf2f((ushortT)v3[j]));
        }
        for (; e < e1; e++){
            u16x8 v = *reinterpret_cast<const u16x8*>(hbf + (long)src_sorted[e]*DH + co);
#pragma unroll
            for (int j = 0; j < 8; j++) a[j] += bf2f((ushortT)v[j]);
        }
        u16x8 o;
#pragma unroll
        for (int j = 0; j < 8; j++) o[j] = f2bf(a[j]);
        *reinterpret_cast<u16x8*>(arow + r*DH) = o;
    }
}

// ---------------- weight concat + bf16 convert: Wcat[512][Kp] ----------------

__global__ void convw_k(const float* __restrict__ lw, const float* __restrict__ sw,
                        int d, int Kp, ushortT* __restrict__ Wc){
    int i = blockIdx.x*256 + threadIdx.x;
    if (i < DH*Kp){
        int n = i / Kp, k = i % Kp;
        float v;
        if (k < 7*d)      v = lw[(long)n*7*d + k];
        else if (k < 8*d) v = sw[(long)n*d + (k - 7*d)];
        else              v = 0.f;
        Wc[i] = f2bf(v);
    }
}

// ---------------- MFMA GEMM: BM=256 x BN=256, 8 waves (512 thr), fused col-stats --------------
// Per-wave 64x128 (4x8 of 16x16x32). Staged bytes minimized: A x2 + W x(M/256).
// 3-deep LDS pipeline (96 KB), counted vmcnt(4), raw barrier, bijective XCD swizzle
// (the 2 col-tiles of a panel are L2-co-located). C output bf16.

__global__ __launch_bounds__(512)
void gemm_mfma_k(const ushortT* __restrict__ A, int lda, int ntA,
                 const ushortT* __restrict__ hbase, int M,
                 const ushortT* __restrict__ W, int ldw,
                 const float* __restrict__ b1, const float* __restrict__ b2,
                 ushortT* __restrict__ C, int nt, float* __restrict__ sums){
    __shared__ ushortT As[3][256*BK];   // 48 KB
    __shared__ ushortT Bs[3][256*BK];   // 48 KB
    const int t = threadIdx.x;

    // bijective XCD swizzle (m204): panel = l>>1, col-tile = l&1
    const int nwg = gridDim.x;
    int q = nwg >> 3, rmd = nwg & 7;
    int xcd = blockIdx.x & 7, slot = blockIdx.x >> 3;
    int l = xcd*q + min(xcd, rmd) + slot;
    const int bm = (l >> 1)*256;
    const int bn = (l & 1)*256;

    // staging: A and B each 1024 16B-units/tile, 2 per thread each
    const int ar0 = min(bm + (t >> 2), M-1);
    const int ar1 = min(bm + 128 + (t >> 2), M-1);
    const int brw0 = bn + (t >> 2);
    const int brw1 = bn + 128 + (t >> 2);
    const int acu = (t & 3)*8;

    f32x4 acc[4][8];
#pragma unroll
    for (int m = 0; m < 4; m++)
#pragma unroll
        for (int n = 0; n < 8; n++) acc[m][n] = (f32x4){0.f,0.f,0.f,0.f};

    const int w = t >> 6;
    const int lane = t & 63;
    const int wm = w >> 1, wn = w & 1;     // 4 x 2 wave grid of 64x128
    const int r = lane & 15, hi = lane >> 4;

    auto stage = [&](int kt, int b){
        const ushortT* p0;
        const ushortT* p1;
        if (kt < ntA){
            p0 = A + (long)ar0*lda + kt*BK + acu;
            p1 = A + (long)ar1*lda + kt*BK + acu;
        } else {
            int k0 = (kt - ntA)*BK;
            p0 = hbase + (long)ar0*DH + k0 + acu;
            p1 = hbase + (long)ar1*DH + k0 + acu;
        }
        load_lds16(p0, &As[b][t*8]);
        load_lds16(p1, &As[b][(t + 512)*8]);
        load_lds16(W + (long)brw0*ldw + kt*BK + acu, &Bs[b][t*8]);
        load_lds16(W + (long)brw1*ldw + kt*BK + acu, &Bs[b][(t + 512)*8]);
    };

    stage(0, 0);
    stage(1, 1);

    for (int kt = 0; kt < nt; ++kt){
        if (kt + 1 < nt) asm volatile("s_waitcnt vmcnt(4)" ::: "memory");
        else             asm volatile("s_waitcnt vmcnt(0)" ::: "memory");
        __builtin_amdgcn_s_barrier();
        __builtin_amdgcn_sched_barrier(0);
        if (kt + 2 < nt) stage(kt + 2, (kt + 2) % 3);
        const int buf = kt % 3;
        bf16x8 af[4], bfr[8];
#pragma unroll
        for (int m = 0; m < 4; m++)
            af[m] = *reinterpret_cast<const bf16x8*>(&As[buf][(wm*64 + m*16 + r)*BK + hi*8]);
#pragma unroll
        for (int n = 0; n < 8; n++)
            bfr[n] = *reinterpret_cast<const bf16x8*>(&Bs[buf][(wn*128 + n*16 + r)*BK + hi*8]);
#pragma unroll
        for (int m = 0; m < 4; m++)
#pragma unroll
            for (int n = 0; n < 8; n++)
                acc[m][n] = __builtin_amdgcn_mfma_f32_16x16x32_bf16(af[m], bfr[n], acc[m][n], 0, 0, 0);
    }

    // epilogue: bias + bf16 store + fused column stats (on rounded values)
#pragma unroll
    for (int n = 0; n < 8; n++){
        int col = bn + wn*128 + n*16 + r;
        float bb = b1[col] + b2[col];
        float s = 0.f, s2 = 0.f;
#pragma unroll
        for (int m = 0; m < 4; m++){
            int row = bm + wm*64 + m*16 + hi*4;
#pragma unroll
            for (int q2 = 0; q2 < 4; q2++){
                if (row + q2 < M){
                    ushortT u = f2bf(acc[m][n][q2] + bb);
                    C[(long)(row + q2)*DH + col] = u;
                    float vr = bf2f(u);
                    s += vr; s2 = fmaf(vr, vr, s2);
                }
            }
        }
        s  += __shfl_xor(s, 16);  s  += __shfl_xor(s, 32);
        s2 += __shfl_xor(s2, 16); s2 += __shfl_xor(s2, 32);
        if (hi == 0){
            atomicAdd(&sums[col], s);
            atomicAdd(&sums[DH + col], s2);
        }
    }
}

// ---------------- BatchNorm passes (bf16 buffer) ----------------

__global__ void finalize_k(const float* __restrict__ sums, const float* __restrict__ g,
                           const float* __restrict__ b, float* __restrict__ ac){
    int c = blockIdx.x*256 + threadIdx.x;
    if (c < DH){
        float mu  = sums[c] * (1.f/NN);
        float var = sums[DH + c] * (1.f/NN) - mu*mu;
        var = fmaxf(var, 0.f);
        float a = g[c] * rsqrtf(var + EPSB);
        ac[c]      = a;
        ac[DH + c] = fmaf(-mu, a, b[c]);
    }
}

__global__ void bnrelu_k(ushortT* __restrict__ buf, int M, const float* __restrict__ ac,
                         float* __restrict__ sums2){
    int col = blockIdx.x*256 + threadIdx.x;
    int r0 = blockIdx.y*128;
    int r1 = min(r0 + 128, M);
    float a = ac[col], c = ac[DH + col];
    float s = 0.f, s2 = 0.f;
    for (int r = r0; r < r1; r++){
        long idx = (long)r*DH + col;
        float y = fmaxf(fmaf(a, bf2f(buf[idx]), c), 0.f);
        ushortT u = f2bf(y);
        buf[idx] = u;
        float yr = bf2f(u);
        s += yr; s2 = fmaf(yr, yr, s2);
    }
    atomicAdd(&sums2[col], s);
    atomicAdd(&sums2[DH + col], s2);
}

__global__ void bn2write_k(const ushortT* __restrict__ buf, const float* __restrict__ ac,
                           float* __restrict__ out, ushortT* __restrict__ hbf, int layer){
    long i = (long)blockIdx.x*256 + threadIdx.x;
    if (i < (long)NN*DH){
        int r = (int)(i >> 9);
        int c = (int)(i & 511);
        float h = fmaf(ac[c], bf2f(buf[i]), ac[DH + c]);
        out[(long)r*(3*DH) + layer*DH + c] = h;
        hbf[i] = f2bf(h);
    }
}

// ---------------- driver ----------------

extern "C" void kernel_launch(void* const* d_in, const int* in_sizes, int n_in,
                              void* d_out, int out_size, void* d_ws, size_t ws_size,
                              hipStream_t stream){
    const float* x0  = (const float*)d_in[0];
    const int*   src = (const int*)d_in[1];
    const int*   dst = (const int*)d_in[2];
    const int*   rel = (const int*)d_in[3];
    const float* lin_w[3]  = {(const float*)d_in[4],  (const float*)d_in[12], (const float*)d_in[20]};
    const float* self_w[3] = {(const float*)d_in[5],  (const float*)d_in[13], (const float*)d_in[21]};
    const float* lin_b[3]  = {(const float*)d_in[6],  (const float*)d_in[14], (const float*)d_in[22]};
    const float* self_b[3] = {(const float*)d_in[7],  (const float*)d_in[15], (const float*)d_in[23]};
    const float* bn1_g[3]  = {(const float*)d_in[8],  (const float*)d_in[16], (const float*)d_in[24]};
    const float* bn1_b[3]  = {(const float*)d_in[9],  (const float*)d_in[17], (const float*)d_in[25]};
    const float* bn2_g[3]  = {(const float*)d_in[10], (const float*)d_in[18], (const float*)d_in[26]};
    const float* bn2_b[3]  = {(const float*)d_in[11], (const float*)d_in[19], (const float*)d_in[27]};

    char* ws = (char*)d_ws;
    size_t off = 0;
    auto alloc = [&](size_t bytes)->char*{ char* p = ws + off; off = align256(off + bytes); return p; };

    int*     counts     = (int*)alloc((size_t)NSEG*4);
    int*     cursor     = (int*)alloc((size_t)NSEG*4);
    int*     seg_start  = (int*)alloc((size_t)(NSEG+1)*4);
    int*     bsum       = (int*)alloc(1024*4);
    int*     src_sorted = (int*)alloc((size_t)NE*4);
    float*   stats      = (float*)alloc((size_t)8*DH*4);
    float*   sums1 = stats;            float* sums2 = stats + 2*DH;
    float*   ac1   = stats + 4*DH;     float* ac2   = stats + 6*DH;
    ushortT* outbuf = (ushortT*)alloc((size_t)NN*DH*2);
    ushortT* hbf    = (ushortT*)alloc((size_t)NN*DH*2);
    ushortT* Wcat   = (ushortT*)alloc((size_t)DH*4096*2);
    ushortT* Acat0  = (ushortT*)alloc((size_t)NN*192*2);

    // Acat (bf16, chunk x 3584): take the remainder; full NN (~215 MB) if it fits.
    size_t remain = (ws_size > off) ? (ws_size - off) : 0;
    long max_nodes = (long)(remain / ((size_t)KSEG*2));
    int chunk = (int)((max_nodes > NN) ? NN : max_nodes);
    chunk &= ~255;
    if (chunk < 256) chunk = 256;
    ushortT* Acat = (ushortT*)(ws + off);

    // CSR build (graph is layer-invariant)
    hipMemsetAsync(counts, 0, (size_t)NSEG*4, stream);
    hipMemsetAsync(cursor, 0, (size_t)NSEG*4, stream);
    hist_k<<<(NE+255)/256, 256, 0, stream>>>(dst, rel, counts);
    int nb = (NSEG + 1023)/1024;
    scan1_k<<<nb, 256, 0, stream>>>(counts, bsum);
    scan2_k<<<1, 256, 0, stream>>>(bsum, nb, seg_start);
    scan3_k<<<nb, 256, 0, stream>>>(counts, bsum, seg_start);
    scatter_k<<<(NE+255)/256, 256, 0, stream>>>(src, dst, rel, seg_start, cursor, src_sorted);

    for (int layer = 0; layer < 3; layer++){
        int d  = (layer == 0) ? DIN : DH;
        int Kp = (layer == 0) ? 192 : 8*DH;
        convw_k<<<(DH*Kp + 255)/256, 256, 0, stream>>>(lin_w[layer], self_w[layer], d, Kp, Wcat);
        hipMemsetAsync(stats, 0, (size_t)4*DH*4, stream);   // sums1 + sums2

        if (layer == 0){
            segsum21b_k<<<NN, 64, 0, stream>>>(x0, seg_start, src_sorted, Acat0);
            gemm_mfma_k<<<((NN + 255)/256)*2, 512, 0, stream>>>(
                Acat0, 192, 6, Acat0, NN, Wcat, 192,
                lin_b[layer], self_b[layer], outbuf, 6, sums1);
        } else {
            for (int c0 = 0; c0 < NN; c0 += chunk){
                int cn = (NN - c0 < chunk) ? (NN - c0) : chunk;
                segsum_wave_k<<<(cn + 3)/4, 256, 0, stream>>>(
                    hbf, seg_start, src_sorted, Acat, c0, cn);
                gemm_mfma_k<<<((cn + 255)/256)*2, 512, 0, stream>>>(
                    Acat, KSEG, 112, hbf + (long)c0*DH, cn, Wcat, 4096,
                    lin_b[layer], self_b[layer],
                    outbuf + (long)c0*DH, 128, sums1);
            }
        }

        finalize_k<<<2, 256, 0, stream>>>(sums1, bn1_g[layer], bn1_b[layer], ac1);
        bnrelu_k<<<dim3(2, (NN+127)/128), 256, 0, stream>>>(outbuf, NN, ac1, sums2);
        finalize_k<<<2, 256, 0, stream>>>(sums2, bn2_g[layer], bn2_b[layer], ac2);
        bn2write_k<<<((long)NN*DH + 255)/256, 256, 0, stream>>>(outbuf, ac2, (float*)d_out, hbf, layer);
    }
}

// Round 11
// 968.151 us; speedup vs baseline: 1.3129x; 1.3129x over previous
//
#include <hip/hip_runtime.h>

#define NN   30000
#define NE   480000
#define NR   7
#define NSEG (NN*NR)
#define DH   512
#define DIN  21
#define EPSB 1e-5f
#define BK   32
#define KSEG 3584          // 7*512 gathered columns (self handled from hbf)
#define CHMAX 15360        // chunk rows (mult of 128), ~110 MB Acat -> L3-resident

typedef __attribute__((ext_vector_type(8))) short bf16x8;
typedef __attribute__((ext_vector_type(8))) unsigned short u16x8;
typedef __attribute__((ext_vector_type(4))) float f32x4;
typedef unsigned short ushortT;

static inline size_t align256(size_t x){ return (x + 255) & ~(size_t)255; }

__device__ inline float bf2f(ushortT u){
    unsigned int i = ((unsigned int)u) << 16; float f; __builtin_memcpy(&f, &i, 4); return f;
}
__device__ inline ushortT f2bf(float f){
    unsigned int i; __builtin_memcpy(&i, &f, 4);
    unsigned int r = i + 0x7FFFu + ((i >> 16) & 1u);
    return (ushortT)(r >> 16);
}

__device__ inline void load_lds16(const ushortT* g, ushortT* l){
    __builtin_amdgcn_global_load_lds((const __attribute__((address_space(1))) unsigned int*)g,
                                     (__attribute__((address_space(3))) unsigned int*)l,
                                     16, 0, 0);
}

// ---------------- CSR build (counting sort by seg = dst*7+rel) ----------------

__global__ void hist_k(const int* __restrict__ dst, const int* __restrict__ rel,
                       int* __restrict__ counts){
    int e = blockIdx.x*256 + threadIdx.x;
    if (e < NE) atomicAdd(&counts[dst[e]*NR + rel[e]], 1);
}

__global__ void scan1_k(const int* __restrict__ counts, int* __restrict__ bsum){
    __shared__ int sd[256];
    int t = threadIdx.x;
    int base = blockIdx.x*1024 + t*4;
    int s = 0;
#pragma unroll
    for (int i = 0; i < 4; i++){ int idx = base + i; if (idx < NSEG) s += counts[idx]; }
    sd[t] = s; __syncthreads();
    for (int off = 128; off > 0; off >>= 1){
        if (t < off) sd[t] += sd[t+off];
        __syncthreads();
    }
    if (t == 0) bsum[blockIdx.x] = sd[0];
}

__global__ void scan2_k(int* __restrict__ bsum, int nb, int* __restrict__ seg_start){
    __shared__ int sd[256];
    int t = threadIdx.x;
    int v = (t < nb) ? bsum[t] : 0;
    sd[t] = v; __syncthreads();
    for (int off = 1; off < 256; off <<= 1){
        int x = sd[t];
        if (t >= off) x += sd[t-off];
        __syncthreads();
        sd[t] = x; __syncthreads();
    }
    if (t < nb) bsum[t] = (t == 0) ? 0 : sd[t-1];
    if (t == 0) seg_start[NSEG] = NE;
}

__global__ void scan3_k(const int* __restrict__ counts, const int* __restrict__ bsum,
                        int* __restrict__ seg_start){
    __shared__ int sd[256];
    int t = threadIdx.x;
    int base = blockIdx.x*1024 + t*4;
    int v[4]; int s = 0;
#pragma unroll
    for (int i = 0; i < 4; i++){ int idx = base + i; v[i] = (idx < NSEG) ? counts[idx] : 0; s += v[i]; }
    sd[t] = s; __syncthreads();
    for (int off = 1; off < 256; off <<= 1){
        int x = sd[t];
        if (t >= off) x += sd[t-off];
        __syncthreads();
        sd[t] = x; __syncthreads();
    }
    int excl = sd[t] - s + bsum[blockIdx.x];
#pragma unroll
    for (int i = 0; i < 4; i++){
        int idx = base + i;
        if (idx < NSEG){ seg_start[idx] = excl; excl += v[i]; }
    }
}

__global__ void scatter_k(const int* __restrict__ src, const int* __restrict__ dst,
                          const int* __restrict__ rel, const int* __restrict__ seg_start,
                          int* __restrict__ cursor, int* __restrict__ src_sorted){
    int e = blockIdx.x*256 + threadIdx.x;
    if (e < NE){
        int s = dst[e]*NR + rel[e];
        int pos = seg_start[s] + atomicAdd(&cursor[s], 1);
        src_sorted[pos] = src[e];
    }
}

// ---------------- layer 0: segment sum d=21, Kp=192 (147 upd | 21 self | 24 pad) ----------------

__global__ void segsum21b_k(const float* __restrict__ x0,
                            const int* __restrict__ seg_start, const int* __restrict__ src_sorted,
                            ushortT* __restrict__ Acat){
    int n = blockIdx.x;
    int t = threadIdx.x;   // 64
    ushortT* arow = Acat + (long)n*192;
    if (t < DIN){
        int sb = n*NR;
        int e0 = seg_start[sb];
#pragma unroll
        for (int r = 0; r < NR; r++){
            int e1 = seg_start[sb + r + 1];
            float a = 0.f;
            for (int e = e0; e < e1; e++) a += x0[(long)src_sorted[e]*DIN + t];
            e0 = e1;
            arow[r*DIN + t] = f2bf(a);
        }
        arow[7*DIN + t] = f2bf(x0[(long)n*DIN + t]);
    }
    if (t >= 40) arow[168 + (t - 40)] = 0;   // zero pad cols 168..191
}

// ---------------- segsum body (layers 1,2): one WAVE per node → Acat[*,3584] ----------------
// 64 lanes x ushort8 = full 512-col row per load; wave-uniform edge loop; 4-way unrolled (MLP).

__device__ inline void segsum_body(const ushortT* __restrict__ hbf,
                                   const int* __restrict__ seg_start,
                                   const int* __restrict__ src_sorted,
                                   ushortT* __restrict__ Acat,
                                   int wid, int c0, int lane){
    const int n = c0 + wid;
    const int co = lane*8;

    int sb[8];
#pragma unroll
    for (int i = 0; i < 8; i++) sb[i] = seg_start[n*NR + i];

    ushortT* arow = Acat + (long)wid*KSEG + co;
#pragma unroll
    for (int r = 0; r < NR; r++){
        float a[8];
#pragma unroll
        for (int j = 0; j < 8; j++) a[j] = 0.f;
        int e = sb[r], e1 = sb[r+1];
        for (; e + 3 < e1; e += 4){
            u16x8 v0 = *reinterpret_cast<const u16x8*>(hbf + (long)src_sorted[e  ]*DH + co);
            u16x8 v1 = *reinterpret_cast<const u16x8*>(hbf + (long)src_sorted[e+1]*DH + co);
            u16x8 v2 = *reinterpret_cast<const u16x8*>(hbf + (long)src_sorted[e+2]*DH + co);
            u16x8 v3 = *reinterpret_cast<const u16x8*>(hbf + (long)src_sorted[e+3]*DH + co);
#pragma unroll
            for (int j = 0; j < 8; j++)
                a[j] += (bf2f((ushortT)v0[j]) + bf2f((ushortT)v1[j]))
                      + (bf2f((ushortT)v2[j]) + bf2f((ushortT)v3[j]));
        }
        for (; e < e1; e++){
            u16x8 v = *reinterpret_cast<const u16x8*>(hbf + (long)src_sorted[e]*DH + co);
#pragma unroll
            for (int j = 0; j < 8; j++) a[j] += bf2f((ushortT)v[j]);
        }
        u16x8 o;
#pragma unroll
        for (int j = 0; j < 8; j++) o[j] = f2bf(a[j]);
        *reinterpret_cast<u16x8*>(arow + r*DH) = o;
    }
}

__global__ __launch_bounds__(256)
void segsum_wave_k(const ushortT* __restrict__ hbf,
                   const int* __restrict__ seg_start, const int* __restrict__ src_sorted,
                   ushortT* __restrict__ Acat, int c0, int cn){
    int wid = (blockIdx.x*256 + threadIdx.x) >> 6;
    if (wid >= cn) return;
    segsum_body(hbf, seg_start, src_sorted, Acat, wid, c0, threadIdx.x & 63);
}

// ---------------- weight concat + bf16 convert: Wcat[512][Kp] ----------------

__global__ void convw_k(const float* __restrict__ lw, const float* __restrict__ sw,
                        int d, int Kp, ushortT* __restrict__ Wc){
    int i = blockIdx.x*256 + threadIdx.x;
    if (i < DH*Kp){
        int n = i / Kp, k = i % Kp;
        float v;
        if (k < 7*d)      v = lw[(long)n*7*d + k];
        else if (k < 8*d) v = sw[(long)n*d + (k - 7*d)];
        else              v = 0.f;
        Wc[i] = f2bf(v);
    }
}

// ---------------- dual-role: MFMA GEMM (128x128, R7 config) + segsum blocks ----------------
// GEMM blocks [0, gemmBlocks): 4 waves of 64x64, 3-deep LDS pipeline, counted vmcnt(3),
// raw barrier, bijective XCD panel-affinity swizzle. C output bf16, fused col-stats.
// Blocks >= gemmBlocks: segment-sum for the NEXT chunk (hidden under GEMM latency).

__global__ __launch_bounds__(256)
void gemm_seg_k(int gemmBlocks,
                const ushortT* __restrict__ A, int lda, int ntA,
                const ushortT* __restrict__ hbase, int M,
                const ushortT* __restrict__ W, int ldw,
                const float* __restrict__ b1, const float* __restrict__ b2,
                ushortT* __restrict__ C, int nt, float* __restrict__ sums,
                const ushortT* __restrict__ hbf,
                const int* __restrict__ seg_start, const int* __restrict__ src_sorted,
                ushortT* __restrict__ Acat2, int nc0, int ncn){
    __shared__ ushortT As[3][128*BK];   // 24 KB
    __shared__ ushortT Bs[3][128*BK];   // 24 KB
    const int t = threadIdx.x;

    if ((int)blockIdx.x >= gemmBlocks){
        int wid = ((int)blockIdx.x - gemmBlocks)*4 + (t >> 6);
        if (wid < ncn)
            segsum_body(hbf, seg_start, src_sorted, Acat2, wid, nc0, t & 63);
        return;
    }

    // bijective XCD swizzle (m204) over gemmBlocks; panel = l>>2, col-tile = l&3
    const int nwg = gemmBlocks;
    int q = nwg >> 3, rmd = nwg & 7;
    int xcd = blockIdx.x & 7, slot = blockIdx.x >> 3;
    int l = xcd*q + min(xcd, rmd) + slot;
    const int bm = (l >> 2)*128;
    const int bn = (l & 3)*128;

    const int w    = t >> 6;
    const int lane = t & 63;

    int f0 = w*128 + lane, f1 = f0 + 64;
    const int ar0 = min(bm + (f0 >> 2), M-1), ac0 = (f0 & 3)*8;
    const int ar1 = min(bm + (f1 >> 2), M-1), ac1 = (f1 & 3)*8;
    const int br0 = bn + (f0 >> 2), br1 = bn + (f1 >> 2);
    const int d0 = (w*128 +  0)*8;
    const int d1 = (w*128 + 64)*8;

    f32x4 acc[4][4];
#pragma unroll
    for (int m = 0; m < 4; m++)
#pragma unroll
        for (int n = 0; n < 4; n++) acc[m][n] = (f32x4){0.f,0.f,0.f,0.f};

    const int wm = w >> 1, wn = w & 1;
    const int r = lane & 15, hi = lane >> 4;

    auto stage = [&](int kt, int b){
        const ushortT* p0;
        const ushortT* p1;
        if (kt < ntA){
            p0 = A + (long)ar0*lda + kt*BK + ac0;
            p1 = A + (long)ar1*lda + kt*BK + ac1;
        } else {
            int k0 = (kt - ntA)*BK;
            p0 = hbase + (long)ar0*DH + k0 + ac0;
            p1 = hbase + (long)ar1*DH + k0 + ac1;
        }
        load_lds16(p0, &As[b][d0]);
        load_lds16(p1, &As[b][d1]);
        load_lds16(W + (long)br0*ldw + kt*BK + ac0, &Bs[b][d0]);
        load_lds16(W + (long)br1*ldw + kt*BK + ac1, &Bs[b][d1]);
    };

    stage(0, 0);
    if (nt > 1) stage(1, 1);

    for (int kt = 0; kt < nt; ++kt){
        if (kt + 1 < nt) asm volatile("s_waitcnt vmcnt(4)" ::: "memory");
        else             asm volatile("s_waitcnt vmcnt(0)" ::: "memory");
        __builtin_amdgcn_s_barrier();
        __builtin_amdgcn_sched_barrier(0);
        if (kt + 2 < nt) stage(kt + 2, (kt + 2) % 3);
        const int buf = kt % 3;
        bf16x8 af[4], bfr[4];
#pragma unroll
        for (int m = 0; m < 4; m++)
            af[m] = *reinterpret_cast<const bf16x8*>(&As[buf][(wm*64 + m*16 + r)*BK + hi*8]);
#pragma unroll
        for (int n = 0; n < 4; n++)
            bfr[n] = *reinterpret_cast<const bf16x8*>(&Bs[buf][(wn*64 + n*16 + r)*BK + hi*8]);
#pragma unroll
        for (int m = 0; m < 4; m++)
#pragma unroll
            for (int n = 0; n < 4; n++)
                acc[m][n] = __builtin_amdgcn_mfma_f32_16x16x32_bf16(af[m], bfr[n], acc[m][n], 0, 0, 0);
    }

    // epilogue: bias + bf16 store + fused column stats (on rounded values)
#pragma unroll
    for (int n = 0; n < 4; n++){
        int col = bn + wn*64 + n*16 + r;
        float bb = b1[col] + b2[col];
        float s = 0.f, s2 = 0.f;
#pragma unroll
        for (int m = 0; m < 4; m++){
            int row = bm + wm*64 + m*16 + hi*4;
#pragma unroll
            for (int q2 = 0; q2 < 4; q2++){
                if (row + q2 < M){
                    ushortT u = f2bf(acc[m][n][q2] + bb);
                    C[(long)(row + q2)*DH + col] = u;
                    float vr = bf2f(u);
                    s += vr; s2 = fmaf(vr, vr, s2);
                }
            }
        }
        s  += __shfl_xor(s, 16);  s  += __shfl_xor(s, 32);
        s2 += __shfl_xor(s2, 16); s2 += __shfl_xor(s2, 32);
        if (hi == 0){
            atomicAdd(&sums[col], s);
            atomicAdd(&sums[DH + col], s2);
        }
    }
}

// ---------------- BatchNorm passes (bf16 buffer) ----------------

__global__ void finalize_k(const float* __restrict__ sums, const float* __restrict__ g,
                           const float* __restrict__ b, float* __restrict__ ac){
    int c = blockIdx.x*256 + threadIdx.x;
    if (c < DH){
        float mu  = sums[c] * (1.f/NN);
        float var = sums[DH + c] * (1.f/NN) - mu*mu;
        var = fmaxf(var, 0.f);
        float a = g[c] * rsqrtf(var + EPSB);
        ac[c]      = a;
        ac[DH + c] = fmaf(-mu, a, b[c]);
    }
}

__global__ void bnrelu_k(ushortT* __restrict__ buf, int M, const float* __restrict__ ac,
                         float* __restrict__ sums2){
    int col = blockIdx.x*256 + threadIdx.x;
    int r0 = blockIdx.y*128;
    int r1 = min(r0 + 128, M);
    float a = ac[col], c = ac[DH + col];
    float s = 0.f, s2 = 0.f;
    for (int r = r0; r < r1; r++){
        long idx = (long)r*DH + col;
        float y = fmaxf(fmaf(a, bf2f(buf[idx]), c), 0.f);
        ushortT u = f2bf(y);
        buf[idx] = u;
        float yr = bf2f(u);
        s += yr; s2 = fmaf(yr, yr, s2);
    }
    atomicAdd(&sums2[col], s);
    atomicAdd(&sums2[DH + col], s2);
}

__global__ void bn2write_k(const ushortT* __restrict__ buf, const float* __restrict__ ac,
                           float* __restrict__ out, ushortT* __restrict__ hbf, int layer){
    long i = (long)blockIdx.x*256 + threadIdx.x;
    if (i < (long)NN*DH){
        int r = (int)(i >> 9);
        int c = (int)(i & 511);
        float h = fmaf(ac[c], bf2f(buf[i]), ac[DH + c]);
        out[(long)r*(3*DH) + layer*DH + c] = h;
        hbf[i] = f2bf(h);
    }
}

// ---------------- driver ----------------

extern "C" void kernel_launch(void* const* d_in, const int* in_sizes, int n_in,
                              void* d_out, int out_size, void* d_ws, size_t ws_size,
                              hipStream_t stream){
    const float* x0  = (const float*)d_in[0];
    const int*   src = (const int*)d_in[1];
    const int*   dst = (const int*)d_in[2];
    const int*   rel = (const int*)d_in[3];
    const float* lin_w[3]  = {(const float*)d_in[4],  (const float*)d_in[12], (const float*)d_in[20]};
    const float* self_w[3] = {(const float*)d_in[5],  (const float*)d_in[13], (const float*)d_in[21]};
    const float* lin_b[3]  = {(const float*)d_in[6],  (const float*)d_in[14], (const float*)d_in[22]};
    const float* self_b[3] = {(const float*)d_in[7],  (const float*)d_in[15], (const float*)d_in[23]};
    const float* bn1_g[3]  = {(const float*)d_in[8],  (const float*)d_in[16], (const float*)d_in[24]};
    const float* bn1_b[3]  = {(const float*)d_in[9],  (const float*)d_in[17], (const float*)d_in[25]};
    const float* bn2_g[3]  = {(const float*)d_in[10], (const float*)d_in[18], (const float*)d_in[26]};
    const float* bn2_b[3]  = {(const float*)d_in[11], (const float*)d_in[19], (const float*)d_in[27]};

    char* ws = (char*)d_ws;
    size_t off = 0;
    auto alloc = [&](size_t bytes)->char*{ char* p = ws + off; off = align256(off + bytes); return p; };

    int*     counts     = (int*)alloc((size_t)NSEG*4);
    int*     cursor     = (int*)alloc((size_t)NSEG*4);
    int*     seg_start  = (int*)alloc((size_t)(NSEG+1)*4);
    int*     bsum       = (int*)alloc(1024*4);
    int*     src_sorted = (int*)alloc((size_t)NE*4);
    float*   stats      = (float*)alloc((size_t)8*DH*4);
    float*   sums1 = stats;            float* sums2 = stats + 2*DH;
    float*   ac1   = stats + 4*DH;     float* ac2   = stats + 6*DH;
    ushortT* outbuf = (ushortT*)alloc((size_t)NN*DH*2);
    ushortT* hbf    = (ushortT*)alloc((size_t)NN*DH*2);
    ushortT* Wcat   = (ushortT*)alloc((size_t)DH*4096*2);
    ushortT* Acat0  = (ushortT*)alloc((size_t)NN*192*2);

    // two Acat buffers (bf16, chunk x 3584); chunk <= CHMAX for L3 residency.
    size_t remain = (ws_size > off) ? (ws_size - off) : 0;
    long max_nodes = (long)(remain / (2*(size_t)KSEG*2));
    int chunk = (int)((max_nodes > CHMAX) ? CHMAX : max_nodes);
    chunk &= ~127;
    if (chunk < 128) chunk = 128;
    ushortT* AcatA = (ushortT*)(ws + off);
    ushortT* AcatB = AcatA + (size_t)chunk*KSEG;
    ushortT* AcatBuf[2] = {AcatA, AcatB};

    // CSR build (graph is layer-invariant)
    hipMemsetAsync(counts, 0, (size_t)NSEG*4, stream);
    hipMemsetAsync(cursor, 0, (size_t)NSEG*4, stream);
    hist_k<<<(NE+255)/256, 256, 0, stream>>>(dst, rel, counts);
    int nb = (NSEG + 1023)/1024;
    scan1_k<<<nb, 256, 0, stream>>>(counts, bsum);
    scan2_k<<<1, 256, 0, stream>>>(bsum, nb, seg_start);
    scan3_k<<<nb, 256, 0, stream>>>(counts, bsum, seg_start);
    scatter_k<<<(NE+255)/256, 256, 0, stream>>>(src, dst, rel, seg_start, cursor, src_sorted);

    const int MB = (NN + 127)/128;   // 235 row panels
    const int nch = (NN + chunk - 1)/chunk;

    for (int layer = 0; layer < 3; layer++){
        int d  = (layer == 0) ? DIN : DH;
        int Kp = (layer == 0) ? 192 : 8*DH;
        convw_k<<<(DH*Kp + 255)/256, 256, 0, stream>>>(lin_w[layer], self_w[layer], d, Kp, Wcat);
        hipMemsetAsync(stats, 0, (size_t)4*DH*4, stream);   // sums1 + sums2

        if (layer == 0){
            segsum21b_k<<<NN, 64, 0, stream>>>(x0, seg_start, src_sorted, Acat0);
            gemm_seg_k<<<MB*4, 256, 0, stream>>>(
                MB*4, Acat0, 192, 6, Acat0, NN, Wcat, 192,
                lin_b[layer], self_b[layer], outbuf, 6, sums1,
                hbf, seg_start, src_sorted, (ushortT*)nullptr, 0, 0);
        } else {
            int cn0 = (NN < chunk) ? NN : chunk;
            segsum_wave_k<<<(cn0 + 3)/4, 256, 0, stream>>>(
                hbf, seg_start, src_sorted, AcatBuf[0], 0, cn0);
            for (int i = 0; i < nch; i++){
                int cc0 = i*chunk;
                int ccn = (NN - cc0 < chunk) ? (NN - cc0) : chunk;
                int gemmBlocks = ((ccn + 127)/128)*4;
                int segBlocks = 0, nc0 = 0, ncn = 0;
                ushortT* An = nullptr;
                if (i + 1 < nch){
                    nc0 = (i + 1)*chunk;
                    ncn = (NN - nc0 < chunk) ? (NN - nc0) : chunk;
                    segBlocks = (ncn + 3)/4;
                    An = AcatBuf[(i + 1) & 1];
                }
                gemm_seg_k<<<gemmBlocks + segBlocks, 256, 0, stream>>>(
                    gemmBlocks, AcatBuf[i & 1], KSEG, 112, hbf + (long)cc0*DH, ccn,
                    Wcat, 4096, lin_b[layer], self_b[layer],
                    outbuf + (long)cc0*DH, 128, sums1,
                    hbf, seg_start, src_sorted, An, nc0, ncn);
            }
        }

        finalize_k<<<2, 256, 0, stream>>>(sums1, bn1_g[layer], bn1_b[layer], ac1);
        bnrelu_k<<<dim3(2, (NN+127)/128), 256, 0, stream>>>(outbuf, NN, ac1, sums2);
        finalize_k<<<2, 256, 0, stream>>>(sums2, bn2_g[layer], bn2_b[layer], ac2);
        bn2write_k<<<((long)NN*DH + 255)/256, 256, 0, stream>>>(outbuf, ac2, (float*)d_out, hbf, layer);
    }
}

// Round 12
// 953.615 us; speedup vs baseline: 1.3329x; 1.0152x over previous
//
#include <hip/hip_runtime.h>

#define NN   30000
#define NE   480000
#define NR   7
#define NSEG (NN*NR)
#define DH   512
#define DIN  21
#define EPSB 1e-5f
#define BK   32
#define KSEG 3584          // 7*512 gathered columns (self handled from hbf)
#define CHMAX 15360        // chunk rows (mult of 128), ~110 MB Acat -> L3-resident

typedef __attribute__((ext_vector_type(8))) short bf16x8;
typedef __attribute__((ext_vector_type(8))) unsigned short u16x8;
typedef __attribute__((ext_vector_type(4))) float f32x4;
typedef unsigned short ushortT;

static inline size_t align256(size_t x){ return (x + 255) & ~(size_t)255; }

__device__ inline float bf2f(ushortT u){
    unsigned int i = ((unsigned int)u) << 16; float f; __builtin_memcpy(&f, &i, 4); return f;
}
__device__ inline ushortT f2bf(float f){
    unsigned int i; __builtin_memcpy(&i, &f, 4);
    unsigned int r = i + 0x7FFFu + ((i >> 16) & 1u);
    return (ushortT)(r >> 16);
}

__device__ inline void load_lds16(const ushortT* g, ushortT* l){
    __builtin_amdgcn_global_load_lds((const __attribute__((address_space(1))) unsigned int*)g,
                                     (__attribute__((address_space(3))) unsigned int*)l,
                                     16, 0, 0);
}

// ---------------- CSR build (counting sort by seg = dst*7+rel) ----------------

__global__ void hist_k(const int* __restrict__ dst, const int* __restrict__ rel,
                       int* __restrict__ counts){
    int e = blockIdx.x*256 + threadIdx.x;
    if (e < NE) atomicAdd(&counts[dst[e]*NR + rel[e]], 1);
}

__global__ void scan1_k(const int* __restrict__ counts, int* __restrict__ bsum){
    __shared__ int sd[256];
    int t = threadIdx.x;
    int base = blockIdx.x*1024 + t*4;
    int s = 0;
#pragma unroll
    for (int i = 0; i < 4; i++){ int idx = base + i; if (idx < NSEG) s += counts[idx]; }
    sd[t] = s; __syncthreads();
    for (int off = 128; off > 0; off >>= 1){
        if (t < off) sd[t] += sd[t+off];
        __syncthreads();
    }
    if (t == 0) bsum[blockIdx.x] = sd[0];
}

__global__ void scan2_k(int* __restrict__ bsum, int nb, int* __restrict__ seg_start){
    __shared__ int sd[256];
    int t = threadIdx.x;
    int v = (t < nb) ? bsum[t] : 0;
    sd[t] = v; __syncthreads();
    for (int off = 1; off < 256; off <<= 1){
        int x = sd[t];
        if (t >= off) x += sd[t-off];
        __syncthreads();
        sd[t] = x; __syncthreads();
    }
    if (t < nb) bsum[t] = (t == 0) ? 0 : sd[t-1];
    if (t == 0) seg_start[NSEG] = NE;
}

__global__ void scan3_k(const int* __restrict__ counts, const int* __restrict__ bsum,
                        int* __restrict__ seg_start){
    __shared__ int sd[256];
    int t = threadIdx.x;
    int base = blockIdx.x*1024 + t*4;
    int v[4]; int s = 0;
#pragma unroll
    for (int i = 0; i < 4; i++){ int idx = base + i; v[i] = (idx < NSEG) ? counts[idx] : 0; s += v[i]; }
    sd[t] = s; __syncthreads();
    for (int off = 1; off < 256; off <<= 1){
        int x = sd[t];
        if (t >= off) x += sd[t-off];
        __syncthreads();
        sd[t] = x; __syncthreads();
    }
    int excl = sd[t] - s + bsum[blockIdx.x];
#pragma unroll
    for (int i = 0; i < 4; i++){
        int idx = base + i;
        if (idx < NSEG){ seg_start[idx] = excl; excl += v[i]; }
    }
}

__global__ void scatter_k(const int* __restrict__ src, const int* __restrict__ dst,
                          const int* __restrict__ rel, const int* __restrict__ seg_start,
                          int* __restrict__ cursor, int* __restrict__ src_sorted){
    int e = blockIdx.x*256 + threadIdx.x;
    if (e < NE){
        int s = dst[e]*NR + rel[e];
        int pos = seg_start[s] + atomicAdd(&cursor[s], 1);
        src_sorted[pos] = src[e];
    }
}

// ---------------- layer 0: segment sum d=21, Kp=192 (147 upd | 21 self | 24 pad) ----------------

__global__ void segsum21b_k(const float* __restrict__ x0,
                            const int* __restrict__ seg_start, const int* __restrict__ src_sorted,
                            ushortT* __restrict__ Acat){
    int n = blockIdx.x;
    int t = threadIdx.x;   // 64
    ushortT* arow = Acat + (long)n*192;
    if (t < DIN){
        int sb = n*NR;
        int e0 = seg_start[sb];
#pragma unroll
        for (int r = 0; r < NR; r++){
            int e1 = seg_start[sb + r + 1];
            float a = 0.f;
            for (int e = e0; e < e1; e++) a += x0[(long)src_sorted[e]*DIN + t];
            e0 = e1;
            arow[r*DIN + t] = f2bf(a);
        }
        arow[7*DIN + t] = f2bf(x0[(long)n*DIN + t]);
    }
    if (t >= 40) arow[168 + (t - 40)] = 0;   // zero pad cols 168..191
}

// ---------------- segsum body (layers 1,2): one WAVE per node → Acat[*,3584] ----------------
// 64 lanes x ushort8 = full 512-col row per load; wave-uniform edge loop; 4-way unrolled (MLP).

__device__ inline void segsum_body(const ushortT* __restrict__ hbf,
                                   const int* __restrict__ seg_start,
                                   const int* __restrict__ src_sorted,
                                   ushortT* __restrict__ Acat,
                                   int wid, int c0, int lane){
    const int n = c0 + wid;
    const int co = lane*8;

    int sb[8];
#pragma unroll
    for (int i = 0; i < 8; i++) sb[i] = seg_start[n*NR + i];

    ushortT* arow = Acat + (long)wid*KSEG + co;
#pragma unroll
    for (int r = 0; r < NR; r++){
        float a[8];
#pragma unroll
        for (int j = 0; j < 8; j++) a[j] = 0.f;
        int e = sb[r], e1 = sb[r+1];
        for (; e + 3 < e1; e += 4){
            u16x8 v0 = *reinterpret_cast<const u16x8*>(hbf + (long)src_sorted[e  ]*DH + co);
            u16x8 v1 = *reinterpret_cast<const u16x8*>(hbf + (long)src_sorted[e+1]*DH + co);
            u16x8 v2 = *reinterpret_cast<const u16x8*>(hbf + (long)src_sorted[e+2]*DH + co);
            u16x8 v3 = *reinterpret_cast<const u16x8*>(hbf + (long)src_sorted[e+3]*DH + co);
#pragma unroll
            for (int j = 0; j < 8; j++)
                a[j] += (bf2f((ushortT)v0[j]) + bf2f((ushortT)v1[j]))
                      + (bf2f((ushortT)v2[j]) + bf2f((ushortT)v3[j]));
        }
        for (; e < e1; e++){
            u16x8 v = *reinterpret_cast<const u16x8*>(hbf + (long)src_sorted[e]*DH + co);
#pragma unroll
            for (int j = 0; j < 8; j++) a[j] += bf2f((ushortT)v[j]);
        }
        u16x8 o;
#pragma unroll
        for (int j = 0; j < 8; j++) o[j] = f2bf(a[j]);
        *reinterpret_cast<u16x8*>(arow + r*DH) = o;
    }
}

__global__ __launch_bounds__(256)
void segsum_wave_k(const ushortT* __restrict__ hbf,
                   const int* __restrict__ seg_start, const int* __restrict__ src_sorted,
                   ushortT* __restrict__ Acat, int c0, int cn){
    int wid = (blockIdx.x*256 + threadIdx.x) >> 6;
    if (wid >= cn) return;
    segsum_body(hbf, seg_start, src_sorted, Acat, wid, c0, threadIdx.x & 63);
}

// ---------------- weight concat + bf16 convert: Wcat[512][Kp] ----------------

__global__ void convw_k(const float* __restrict__ lw, const float* __restrict__ sw,
                        int d, int Kp, ushortT* __restrict__ Wc){
    int i = blockIdx.x*256 + threadIdx.x;
    if (i < DH*Kp){
        int n = i / Kp, k = i % Kp;
        float v;
        if (k < 7*d)      v = lw[(long)n*7*d + k];
        else if (k < 8*d) v = sw[(long)n*d + (k - 7*d)];
        else              v = 0.f;
        Wc[i] = f2bf(v);
    }
}

// ---------------- dual-role: MFMA GEMM (128x128) + segsum blocks ----------------
// T2 LDS swizzle (rule #21: linear gload_lds dest + inverse-swizzled global SOURCE +
// swizzled ds_read): unit f holds k-chunk (f&3)^((f>>3)&3); read offset (hi^((r>>1)&3))*8.
// Turns the 8-way ds_read_b128 bank conflict into 2-way (free).
// GEMM blocks [0,gemmBlocks): 4 waves of 64x64, 3-deep pipeline, counted vmcnt, raw barrier,
// bijective XCD panel swizzle, bf16 C + fused col-stats. Rest: segsum for next chunk.

__global__ __launch_bounds__(256)
void gemm_seg_k(int gemmBlocks,
                const ushortT* __restrict__ A, int lda, int ntA,
                const ushortT* __restrict__ hbase, int M,
                const ushortT* __restrict__ W, int ldw,
                const float* __restrict__ b1, const float* __restrict__ b2,
                ushortT* __restrict__ C, int nt, float* __restrict__ sums,
                const ushortT* __restrict__ hbf,
                const int* __restrict__ seg_start, const int* __restrict__ src_sorted,
                ushortT* __restrict__ Acat2, int nc0, int ncn){
    __shared__ ushortT As[3][128*BK];   // 24 KB
    __shared__ ushortT Bs[3][128*BK];   // 24 KB
    const int t = threadIdx.x;

    if ((int)blockIdx.x >= gemmBlocks){
        int wid = ((int)blockIdx.x - gemmBlocks)*4 + (t >> 6);
        if (wid < ncn)
            segsum_body(hbf, seg_start, src_sorted, Acat2, wid, nc0, t & 63);
        return;
    }

    // bijective XCD swizzle (m204) over gemmBlocks; panel = l>>2, col-tile = l&3
    const int nwg = gemmBlocks;
    int q = nwg >> 3, rmd = nwg & 7;
    int xcd = blockIdx.x & 7, slot = blockIdx.x >> 3;
    int l = xcd*q + min(xcd, rmd) + slot;
    const int bm = (l >> 2)*128;
    const int bn = (l & 3)*128;

    const int w    = t >> 6;
    const int lane = t & 63;

    int f0 = w*128 + lane, f1 = f0 + 64;
    // T2: swizzled k-chunk for the global source of LDS unit f
    const int ac0 = (((f0 & 3) ^ ((f0 >> 3) & 3)))*8;
    const int ac1 = (((f1 & 3) ^ ((f1 >> 3) & 3)))*8;
    const int ar0 = min(bm + (f0 >> 2), M-1);
    const int ar1 = min(bm + (f1 >> 2), M-1);
    const int br0 = bn + (f0 >> 2), br1 = bn + (f1 >> 2);
    const int d0 = (w*128 +  0)*8;
    const int d1 = (w*128 + 64)*8;

    f32x4 acc[4][4];
#pragma unroll
    for (int m = 0; m < 4; m++)
#pragma unroll
        for (int n = 0; n < 4; n++) acc[m][n] = (f32x4){0.f,0.f,0.f,0.f};

    const int wm = w >> 1, wn = w & 1;
    const int r = lane & 15, hi = lane >> 4;
    const int xr = (r >> 1) & 3;            // T2 read-side XOR
    const int ko = (hi ^ xr)*8;

    auto stage = [&](int kt, int b){
        const ushortT* p0;
        const ushortT* p1;
        if (kt < ntA){
            p0 = A + (long)ar0*lda + kt*BK + ac0;
            p1 = A + (long)ar1*lda + kt*BK + ac1;
        } else {
            int k0 = (kt - ntA)*BK;
            p0 = hbase + (long)ar0*DH + k0 + ac0;
            p1 = hbase + (long)ar1*DH + k0 + ac1;
        }
        load_lds16(p0, &As[b][d0]);
        load_lds16(p1, &As[b][d1]);
        load_lds16(W + (long)br0*ldw + kt*BK + ac0, &Bs[b][d0]);
        load_lds16(W + (long)br1*ldw + kt*BK + ac1, &Bs[b][d1]);
    };

    stage(0, 0);
    if (nt > 1) stage(1, 1);

    for (int kt = 0; kt < nt; ++kt){
        if (kt + 1 < nt) asm volatile("s_waitcnt vmcnt(4)" ::: "memory");
        else             asm volatile("s_waitcnt vmcnt(0)" ::: "memory");
        __builtin_amdgcn_s_barrier();
        __builtin_amdgcn_sched_barrier(0);
        if (kt + 2 < nt) stage(kt + 2, (kt + 2) % 3);
        const int buf = kt % 3;
        bf16x8 af[4], bfr[4];
#pragma unroll
        for (int m = 0; m < 4; m++)
            af[m] = *reinterpret_cast<const bf16x8*>(&As[buf][(wm*64 + m*16 + r)*BK + ko]);
#pragma unroll
        for (int n = 0; n < 4; n++)
            bfr[n] = *reinterpret_cast<const bf16x8*>(&Bs[buf][(wn*64 + n*16 + r)*BK + ko]);
#pragma unroll
        for (int m = 0; m < 4; m++)
#pragma unroll
            for (int n = 0; n < 4; n++)
                acc[m][n] = __builtin_amdgcn_mfma_f32_16x16x32_bf16(af[m], bfr[n], acc[m][n], 0, 0, 0);
    }

    // epilogue: bias + bf16 store + fused column stats (on rounded values)
#pragma unroll
    for (int n = 0; n < 4; n++){
        int col = bn + wn*64 + n*16 + r;
        float bb = b1[col] + b2[col];
        float s = 0.f, s2 = 0.f;
#pragma unroll
        for (int m = 0; m < 4; m++){
            int row = bm + wm*64 + m*16 + hi*4;
#pragma unroll
            for (int q2 = 0; q2 < 4; q2++){
                if (row + q2 < M){
                    ushortT u = f2bf(acc[m][n][q2] + bb);
                    C[(long)(row + q2)*DH + col] = u;
                    float vr = bf2f(u);
                    s += vr; s2 = fmaf(vr, vr, s2);
                }
            }
        }
        s  += __shfl_xor(s, 16);  s  += __shfl_xor(s, 32);
        s2 += __shfl_xor(s2, 16); s2 += __shfl_xor(s2, 32);
        if (hi == 0){
            atomicAdd(&sums[col], s);
            atomicAdd(&sums[DH + col], s2);
        }
    }
}

// ---------------- BatchNorm passes (bf16 buffer) ----------------

__global__ void finalize_k(const float* __restrict__ sums, const float* __restrict__ g,
                           const float* __restrict__ b, float* __restrict__ ac){
    int c = blockIdx.x*256 + threadIdx.x;
    if (c < DH){
        float mu  = sums[c] * (1.f/NN);
        float var = sums[DH + c] * (1.f/NN) - mu*mu;
        var = fmaxf(var, 0.f);
        float a = g[c] * rsqrtf(var + EPSB);
        ac[c]      = a;
        ac[DH + c] = fmaf(-mu, a, b[c]);
    }
}

__global__ void bnrelu_k(ushortT* __restrict__ buf, int M, const float* __restrict__ ac,
                         float* __restrict__ sums2){
    int col = blockIdx.x*256 + threadIdx.x;
    int r0 = blockIdx.y*128;
    int r1 = min(r0 + 128, M);
    float a = ac[col], c = ac[DH + col];
    float s = 0.f, s2 = 0.f;
    for (int r = r0; r < r1; r++){
        long idx = (long)r*DH + col;
        float y = fmaxf(fmaf(a, bf2f(buf[idx]), c), 0.f);
        ushortT u = f2bf(y);
        buf[idx] = u;
        float yr = bf2f(u);
        s += yr; s2 = fmaf(yr, yr, s2);
    }
    atomicAdd(&sums2[col], s);
    atomicAdd(&sums2[DH + col], s2);
}

__global__ void bn2write_k(const ushortT* __restrict__ buf, const float* __restrict__ ac,
                           float* __restrict__ out, ushortT* __restrict__ hbf, int layer){
    long i = (long)blockIdx.x*256 + threadIdx.x;
    if (i < (long)NN*DH){
        int r = (int)(i >> 9);
        int c = (int)(i & 511);
        float h = fmaf(ac[c], bf2f(buf[i]), ac[DH + c]);
        out[(long)r*(3*DH) + layer*DH + c] = h;
        hbf[i] = f2bf(h);
    }
}

// ---------------- driver ----------------

extern "C" void kernel_launch(void* const* d_in, const int* in_sizes, int n_in,
                              void* d_out, int out_size, void* d_ws, size_t ws_size,
                              hipStream_t stream){
    const float* x0  = (const float*)d_in[0];
    const int*   src = (const int*)d_in[1];
    const int*   dst = (const int*)d_in[2];
    const int*   rel = (const int*)d_in[3];
    const float* lin_w[3]  = {(const float*)d_in[4],  (const float*)d_in[12], (const float*)d_in[20]};
    const float* self_w[3] = {(const float*)d_in[5],  (const float*)d_in[13], (const float*)d_in[21]};
    const float* lin_b[3]  = {(const float*)d_in[6],  (const float*)d_in[14], (const float*)d_in[22]};
    const float* self_b[3] = {(const float*)d_in[7],  (const float*)d_in[15], (const float*)d_in[23]};
    const float* bn1_g[3]  = {(const float*)d_in[8],  (const float*)d_in[16], (const float*)d_in[24]};
    const float* bn1_b[3]  = {(const float*)d_in[9],  (const float*)d_in[17], (const float*)d_in[25]};
    const float* bn2_g[3]  = {(const float*)d_in[10], (const float*)d_in[18], (const float*)d_in[26]};
    const float* bn2_b[3]  = {(const float*)d_in[11], (const float*)d_in[19], (const float*)d_in[27]};

    char* ws = (char*)d_ws;
    size_t off = 0;
    auto alloc = [&](size_t bytes)->char*{ char* p = ws + off; off = align256(off + bytes); return p; };

    int*     counts     = (int*)alloc((size_t)NSEG*4);
    int*     cursor     = (int*)alloc((size_t)NSEG*4);
    int*     seg_start  = (int*)alloc((size_t)(NSEG+1)*4);
    int*     bsum       = (int*)alloc(1024*4);
    int*     src_sorted = (int*)alloc((size_t)NE*4);
    float*   stats      = (float*)alloc((size_t)8*DH*4);
    float*   sums1 = stats;            float* sums2 = stats + 2*DH;
    float*   ac1   = stats + 4*DH;     float* ac2   = stats + 6*DH;
    ushortT* outbuf = (ushortT*)alloc((size_t)NN*DH*2);
    ushortT* hbf    = (ushortT*)alloc((size_t)NN*DH*2);
    ushortT* Wcat   = (ushortT*)alloc((size_t)DH*4096*2);
    ushortT* Acat0  = (ushortT*)alloc((size_t)NN*192*2);

    // two Acat buffers (bf16, chunk x 3584); chunk <= CHMAX for L3 residency.
    size_t remain = (ws_size > off) ? (ws_size - off) : 0;
    long max_nodes = (long)(remain / (2*(size_t)KSEG*2));
    int chunk = (int)((max_nodes > CHMAX) ? CHMAX : max_nodes);
    chunk &= ~127;
    if (chunk < 128) chunk = 128;
    ushortT* AcatA = (ushortT*)(ws + off);
    ushortT* AcatB = AcatA + (size_t)chunk*KSEG;
    ushortT* AcatBuf[2] = {AcatA, AcatB};

    // CSR build (graph is layer-invariant)
    hipMemsetAsync(counts, 0, (size_t)NSEG*4, stream);
    hipMemsetAsync(cursor, 0, (size_t)NSEG*4, stream);
    hist_k<<<(NE+255)/256, 256, 0, stream>>>(dst, rel, counts);
    int nb = (NSEG + 1023)/1024;
    scan1_k<<<nb, 256, 0, stream>>>(counts, bsum);
    scan2_k<<<1, 256, 0, stream>>>(bsum, nb, seg_start);
    scan3_k<<<nb, 256, 0, stream>>>(counts, bsum, seg_start);
    scatter_k<<<(NE+255)/256, 256, 0, stream>>>(src, dst, rel, seg_start, cursor, src_sorted);

    const int MB = (NN + 127)/128;   // 235 row panels
    const int nch = (NN + chunk - 1)/chunk;

    for (int layer = 0; layer < 3; layer++){
        int d  = (layer == 0) ? DIN : DH;
        int Kp = (layer == 0) ? 192 : 8*DH;
        convw_k<<<(DH*Kp + 255)/256, 256, 0, stream>>>(lin_w[layer], self_w[layer], d, Kp, Wcat);
        hipMemsetAsync(stats, 0, (size_t)4*DH*4, stream);   // sums1 + sums2

        if (layer == 0){
            segsum21b_k<<<NN, 64, 0, stream>>>(x0, seg_start, src_sorted, Acat0);
            gemm_seg_k<<<MB*4, 256, 0, stream>>>(
                MB*4, Acat0, 192, 6, Acat0, NN, Wcat, 192,
                lin_b[layer], self_b[layer], outbuf, 6, sums1,
                hbf, seg_start, src_sorted, (ushortT*)nullptr, 0, 0);
        } else {
            int cn0 = (NN < chunk) ? NN : chunk;
            segsum_wave_k<<<(cn0 + 3)/4, 256, 0, stream>>>(
                hbf, seg_start, src_sorted, AcatBuf[0], 0, cn0);
            for (int i = 0; i < nch; i++){
                int cc0 = i*chunk;
                int ccn = (NN - cc0 < chunk) ? (NN - cc0) : chunk;
                int gemmBlocks = ((ccn + 127)/128)*4;
                int segBlocks = 0, nc0 = 0, ncn = 0;
                ushortT* An = nullptr;
                if (i + 1 < nch){
                    nc0 = (i + 1)*chunk;
                    ncn = (NN - nc0 < chunk) ? (NN - nc0) : chunk;
                    segBlocks = (ncn + 3)/4;
                    An = AcatBuf[(i + 1) & 1];
                }
                gemm_seg_k<<<gemmBlocks + segBlocks, 256, 0, stream>>>(
                    gemmBlocks, AcatBuf[i & 1], KSEG, 112, hbf + (long)cc0*DH, ccn,
                    Wcat, 4096, lin_b[layer], self_b[layer],
                    outbuf + (long)cc0*DH, 128, sums1,
                    hbf, seg_start, src_sorted, An, nc0, ncn);
            }
        }

        finalize_k<<<2, 256, 0, stream>>>(sums1, bn1_g[layer], bn1_b[layer], ac1);
        bnrelu_k<<<dim3(2, (NN+127)/128), 256, 0, stream>>>(outbuf, NN, ac1, sums2);
        finalize_k<<<2, 256, 0, stream>>>(sums2, bn2_g[layer], bn2_b[layer], ac2);
        bn2write_k<<<((long)NN*DH + 255)/256, 256, 0, stream>>>(outbuf, ac2, (float*)d_out, hbf, layer);
    }
}